// Round 4
// baseline (1200.682 us; speedup 1.0000x reference)
//
#include <hip/hip_runtime.h>
#include <hip/hip_fp16.h>

#define NN 100000
#define NE 1600000
#define BK 512          // nodes per bucket (CSR build)
#define BKSH 9          // log2(BK)
#define NBKT 196        // ceil(NN/BK)
#define KCH 4           // src chunks for convoyed aggregation
#define CHMAG 171799u   // ceil(2^32/25000): chunk = umulhi(src, CHMAG) = src/25000

// ---------------- Bucketed CSR build ----------------

__global__ __launch_bounds__(256) void zero_small_kernel(int* __restrict__ p, int n) {
    int i = threadIdx.x + blockIdx.x * 256;
    if (i < n) p[i] = 0;
}

__global__ __launch_bounds__(256) void bhist_kernel(const int* __restrict__ dst,
                                                    int* __restrict__ bcnt, int e) {
    __shared__ int h[NBKT];
    for (int i = threadIdx.x; i < NBKT; i += 256) h[i] = 0;
    __syncthreads();
    for (int i = blockIdx.x * 256 + threadIdx.x; i < e; i += gridDim.x * 256)
        atomicAdd(&h[dst[i] >> BKSH], 1);
    __syncthreads();
    for (int i = threadIdx.x; i < NBKT; i += 256)
        if (h[i]) atomicAdd(&bcnt[i], h[i]);
}

__global__ __launch_bounds__(256) void bscan_kernel(const int* __restrict__ bcnt,
                                                    int* __restrict__ bbase,
                                                    int* __restrict__ bcur) {
    __shared__ int sc[256];
    int tid = threadIdx.x;
    int v = (tid < NBKT) ? bcnt[tid] : 0;
    sc[tid] = v;
    __syncthreads();
    for (int off = 1; off < 256; off <<= 1) {
        int t2 = (tid >= off) ? sc[tid - off] : 0;
        __syncthreads();
        sc[tid] += t2;
        __syncthreads();
    }
    if (tid < NBKT) {
        int ex = sc[tid] - v;
        bbase[tid] = ex;
        bcur[tid] = ex;
    }
    if (tid == 255) bbase[NBKT] = sc[255];
}

// Counting-sort edges into dst-bucket order. Tile = 2048 edges, LDS reorder.
__global__ __launch_bounds__(256) void bscatter_kernel(const int* __restrict__ src,
                                                       const int* __restrict__ dst,
                                                       int* __restrict__ bcur,
                                                       int2* __restrict__ bedges, int e) {
    __shared__ int h[256];
    __shared__ int sc[256];
    __shared__ int gb[NBKT];
    __shared__ int2 stage[2048];
    int tid = threadIdx.x;
    for (int tile = blockIdx.x * 2048; tile < e; tile += gridDim.x * 2048) {
        int cnt_tile = min(2048, e - tile);
        h[tid] = 0;
        __syncthreads();
        int2 pr[8]; int rk[8]; int bk[8];
#pragma unroll
        for (int j = 0; j < 8; j++) {
            int li = tid + j * 256;
            if (li < cnt_tile) {
                pr[j].x = src[tile + li];
                pr[j].y = dst[tile + li];
                bk[j] = pr[j].y >> BKSH;
                rk[j] = atomicAdd(&h[bk[j]], 1);
            } else bk[j] = -1;
        }
        __syncthreads();
        int v = h[tid];
        sc[tid] = v;
        __syncthreads();
        for (int off = 1; off < 256; off <<= 1) {
            int t2 = (tid >= off) ? sc[tid - off] : 0;
            __syncthreads();
            sc[tid] += t2;
            __syncthreads();
        }
        int excl = sc[tid] - v;
        if (tid < NBKT && v > 0) gb[tid] = atomicAdd(&bcur[tid], v);
        __syncthreads();
        sc[tid] = excl;
        __syncthreads();
#pragma unroll
        for (int j = 0; j < 8; j++)
            if (bk[j] >= 0) stage[sc[bk[j]] + rk[j]] = pr[j];
        __syncthreads();
#pragma unroll
        for (int j = 0; j < 8; j++) {
            int li = tid + j * 256;
            if (li < cnt_tile) {
                int2 p2 = stage[li];
                int b = p2.y >> BKSH;
                bedges[gb[b] + (li - sc[b])] = p2;
            }
        }
        __syncthreads();
    }
}

// One block per bucket: per-(node,chunk) LDS hist + scan + cursor placement.
// csr entries for each node are grouped by src chunk; ccnt4[v*4+c] = count.
__global__ __launch_bounds__(256) void bfill_kernel(const int2* __restrict__ bedges,
                                                    const int* __restrict__ bbase,
                                                    int* __restrict__ start,
                                                    ushort* __restrict__ ccnt4,
                                                    float* __restrict__ dinv,
                                                    int* __restrict__ csr) {
    __shared__ int lcnt[BK * KCH];   // 8KB
    __shared__ int lsum[256];
    __shared__ int lstart[BK];
    __shared__ int lcur[BK * KCH];   // 8KB
    int q = blockIdx.x, tid = threadIdx.x;
    int ebase = bbase[q], ec = bbase[q + 1] - ebase;
    int nbase = q * BK;
    for (int i = tid; i < BK * KCH; i += 256) lcnt[i] = 0;
    __syncthreads();
    for (int i = tid; i < ec; i += 256) {
        int2 p2 = bedges[ebase + i];
        int ch = __umulhi((unsigned)p2.x, CHMAG);
        atomicAdd(&lcnt[(p2.y - nbase) * KCH + ch], 1);
    }
    __syncthreads();
    int la = 2 * tid, lb = 2 * tid + 1;
    int a = lcnt[la * KCH] + lcnt[la * KCH + 1] + lcnt[la * KCH + 2] + lcnt[la * KCH + 3];
    int b = lcnt[lb * KCH] + lcnt[lb * KCH + 1] + lcnt[lb * KCH + 2] + lcnt[lb * KCH + 3];
    int s = a + b;
    lsum[tid] = s;
    __syncthreads();
    for (int off = 1; off < 256; off <<= 1) {
        int t2 = (tid >= off) ? lsum[tid - off] : 0;
        __syncthreads();
        lsum[tid] += t2;
        __syncthreads();
    }
    int ex = lsum[tid] - s;
    lstart[la] = ex;
    lstart[lb] = ex + a;
    {
        int run = ex;
#pragma unroll
        for (int c = 0; c < KCH; c++) { lcur[la * KCH + c] = run; run += lcnt[la * KCH + c]; }
#pragma unroll
        for (int c = 0; c < KCH; c++) { lcur[lb * KCH + c] = run; run += lcnt[lb * KCH + c]; }
    }
    __syncthreads();
    for (int l = tid; l < BK; l += 256) {
        int v = nbase + l;
        if (v < NN) {
            start[v] = ebase + lstart[l];
            int c0 = lcnt[l * KCH], c1 = lcnt[l * KCH + 1], c2 = lcnt[l * KCH + 2], c3 = lcnt[l * KCH + 3];
            ushort4 cc; cc.x = (ushort)c0; cc.y = (ushort)c1; cc.z = (ushort)c2; cc.w = (ushort)c3;
            *(ushort4*)&ccnt4[(size_t)v * 4] = cc;
            dinv[v] = rsqrtf((float)(c0 + c1 + c2 + c3) + 1.0f);
        }
    }
    for (int i = tid; i < ec; i += 256) {
        int2 p2 = bedges[ebase + i];
        int ch = __umulhi((unsigned)p2.x, CHMAG);
        int r = atomicAdd(&lcur[(p2.y - nbase) * KCH + ch], 1);
        csr[ebase + r] = p2.x;
    }
}

// ---------------- GEMM: s = half( dinv .* (x @ W) ) ----------------
template <int DOUT>
__global__ __launch_bounds__(128) void gemm_kernel(const float* __restrict__ x,
                                                   const float* __restrict__ W,
                                                   const float* __restrict__ dinv,
                                                   __half* __restrict__ s, int n) {
    constexpr int G = DOUT / 16;
    constexpr int R = G;
    constexpr int ROWS = 128;
    __shared__ float xs[ROWS][65];
    __shared__ float ws[64][DOUT];
    int tid = threadIdx.x;
    int row0 = blockIdx.x * ROWS;
    for (int i = tid; i < 64 * DOUT; i += 128) ws[i / DOUT][i % DOUT] = W[i];
    for (int i = tid; i < ROWS * 16; i += 128) {
        int r = i >> 4, c = (i & 15) * 4;
        float4 v = make_float4(0.f, 0.f, 0.f, 0.f);
        if (row0 + r < n) v = *(const float4*)&x[(row0 + r) * 64 + c];
        xs[r][c] = v.x; xs[r][c + 1] = v.y; xs[r][c + 2] = v.z; xs[r][c + 3] = v.w;
    }
    __syncthreads();
    int cg = tid % G;
    int rbase = (tid / G) * R;
    float acc[R][16];
#pragma unroll
    for (int i = 0; i < R; i++)
#pragma unroll
        for (int j = 0; j < 16; j++) acc[i][j] = 0.f;
    for (int k = 0; k < 64; k++) {
        float xv[R];
#pragma unroll
        for (int i = 0; i < R; i++) xv[i] = xs[rbase + i][k];
#pragma unroll
        for (int j = 0; j < 4; j++) {
            float4 wv = *(const float4*)&ws[k][cg * 16 + j * 4];
#pragma unroll
            for (int i = 0; i < R; i++) {
                acc[i][j * 4 + 0] += xv[i] * wv.x;
                acc[i][j * 4 + 1] += xv[i] * wv.y;
                acc[i][j * 4 + 2] += xv[i] * wv.z;
                acc[i][j * 4 + 3] += xv[i] * wv.w;
            }
        }
    }
#pragma unroll
    for (int i = 0; i < R; i++) {
        int r = row0 + rbase + i;
        if (r < n) {
            float dv = dinv[r];
            union { ushort u[16]; uint4 q[2]; } pk;
#pragma unroll
            for (int j = 0; j < 16; j++)
                pk.u[j] = __half_as_ushort(__float2half_rn(acc[i][j] * dv));
            uint4* sp = (uint4*)&s[(size_t)r * DOUT + cg * 16];
            sp[0] = pk.q[0];
            sp[1] = pk.q[1];
        }
    }
}

// ---------------- Convoyed aggregation ----------------
// Persistent grid (1024 blocks = 4/CU, all co-resident). Outer loop over
// src chunks: whole device gathers from one 3.2MB chunk at a time -> L2-hot.
// D=64: 1 node per wave-slot, 25 nodes/wave in register accumulators.
template <bool RELU>
__global__ __launch_bounds__(256) void agg64_kernel(const __half* __restrict__ s,
                                                    const int* __restrict__ csr,
                                                    const int* __restrict__ start,
                                                    const ushort* __restrict__ ccnt4,
                                                    const float* __restrict__ dinv,
                                                    const float* __restrict__ bias,
                                                    float* __restrict__ out) {
    constexpr int NPW = 25;
    int wid = blockIdx.x * 4 + (threadIdx.x >> 6);   // 0..4095
    int lane = threadIdx.x & 63;
    int nb = wid * NPW;
    float acc[NPW];
#pragma unroll
    for (int i = 0; i < NPW; i++) acc[i] = 0.f;
    for (int c = 0; c < KCH; c++) {
#pragma unroll
        for (int i = 0; i < NPW; i++) {
            int node = nb + i;
            if (node < NN) {
                int st = start[node];
                uint2 ccu = *(const uint2*)&ccnt4[(size_t)node * 4];
                int c0 = ccu.x & 0xffff, c1 = (int)(ccu.x >> 16);
                int c2 = ccu.y & 0xffff, c3 = (int)(ccu.y >> 16);
                int off = st + ((c > 0) ? c0 : 0) + ((c > 1) ? c1 : 0) + ((c > 2) ? c2 : 0);
                int cn = (c == 0) ? c0 : ((c == 1) ? c1 : ((c == 2) ? c2 : c3));
                if ((int)__umulhi((unsigned)node, CHMAG) == c)
                    acc[i] += __half2float(s[(size_t)node * 64 + lane]);  // self loop
                int e = 0;
                for (; e + 3 < cn; e += 4) {
                    int u0 = csr[off + e + 0];
                    int u1 = csr[off + e + 1];
                    int u2 = csr[off + e + 2];
                    int u3 = csr[off + e + 3];
                    float a0 = __half2float(s[(size_t)u0 * 64 + lane]);
                    float a1 = __half2float(s[(size_t)u1 * 64 + lane]);
                    float a2 = __half2float(s[(size_t)u2 * 64 + lane]);
                    float a3 = __half2float(s[(size_t)u3 * 64 + lane]);
                    acc[i] += (a0 + a1) + (a2 + a3);
                }
                for (; e < cn; e++) {
                    int u = csr[off + e];
                    acc[i] += __half2float(s[(size_t)u * 64 + lane]);
                }
            }
        }
    }
    float bv = bias[lane];
#pragma unroll
    for (int i = 0; i < NPW; i++) {
        int node = nb + i;
        if (node < NN) {
            float o = dinv[node] * acc[i] + bv;
            if (RELU) o = fmaxf(o, 0.f);
            out[(size_t)node * 64 + lane] = o;
        }
    }
}

// D=16 variant: 4 nodes per wave concurrently (grp = lane>>4), 7 iterations.
__global__ __launch_bounds__(256) void agg16_kernel(const __half* __restrict__ s,
                                                    const int* __restrict__ csr,
                                                    const int* __restrict__ start,
                                                    const ushort* __restrict__ ccnt4,
                                                    const float* __restrict__ dinv,
                                                    const float* __restrict__ bias,
                                                    float* __restrict__ out) {
    constexpr int IT = 7;  // 4096 waves * 4 grp * 7 = 114688 >= NN
    int wid = blockIdx.x * 4 + (threadIdx.x >> 6);
    int lane = threadIdx.x & 63;
    int col = lane & 15;
    int grp = lane >> 4;
    int nb = wid * (4 * IT) + grp;
    float acc[IT];
#pragma unroll
    for (int i = 0; i < IT; i++) acc[i] = 0.f;
    for (int c = 0; c < KCH; c++) {
#pragma unroll
        for (int i = 0; i < IT; i++) {
            int node = nb + i * 4;
            if (node < NN) {
                int st = start[node];
                uint2 ccu = *(const uint2*)&ccnt4[(size_t)node * 4];
                int c0 = ccu.x & 0xffff, c1 = (int)(ccu.x >> 16);
                int c2 = ccu.y & 0xffff, c3 = (int)(ccu.y >> 16);
                int off = st + ((c > 0) ? c0 : 0) + ((c > 1) ? c1 : 0) + ((c > 2) ? c2 : 0);
                int cn = (c == 0) ? c0 : ((c == 1) ? c1 : ((c == 2) ? c2 : c3));
                if ((int)__umulhi((unsigned)node, CHMAG) == c)
                    acc[i] += __half2float(s[(size_t)node * 16 + col]);
                int e = 0;
                for (; e + 3 < cn; e += 4) {
                    int u0 = csr[off + e + 0];
                    int u1 = csr[off + e + 1];
                    int u2 = csr[off + e + 2];
                    int u3 = csr[off + e + 3];
                    float a0 = __half2float(s[(size_t)u0 * 16 + col]);
                    float a1 = __half2float(s[(size_t)u1 * 16 + col]);
                    float a2 = __half2float(s[(size_t)u2 * 16 + col]);
                    float a3 = __half2float(s[(size_t)u3 * 16 + col]);
                    acc[i] += (a0 + a1) + (a2 + a3);
                }
                for (; e < cn; e++) {
                    int u = csr[off + e];
                    acc[i] += __half2float(s[(size_t)u * 16 + col]);
                }
            }
        }
    }
    float bv = bias[col];
#pragma unroll
    for (int i = 0; i < IT; i++) {
        int node = nb + i * 4;
        if (node < NN)
            out[(size_t)node * 16 + col] = dinv[node] * acc[i] + bv;
    }
}

// ---------------- launch ----------------

extern "C" void kernel_launch(void* const* d_in, const int* in_sizes, int n_in,
                              void* d_out, int out_size, void* d_ws, size_t ws_size,
                              hipStream_t stream) {
    const float* x  = (const float*)d_in[0];
    const int* ei   = (const int*)d_in[1];
    const float* W1 = (const float*)d_in[2];
    const float* b1 = (const float*)d_in[3];
    const float* W2 = (const float*)d_in[4];
    const float* b2 = (const float*)d_in[5];
    const float* W3 = (const float*)d_in[6];
    const float* b3 = (const float*)d_in[7];
    const float* W4 = (const float*)d_in[8];
    const float* b4 = (const float*)d_in[9];
    const int* src = ei;
    const int* dst = ei + NE;

    char* w = (char*)d_ws;
    float* dinv   = (float*)w;        w += (size_t)NN * 4;
    int* start    = (int*)w;          w += (size_t)NN * 4;
    ushort* ccnt4 = (ushort*)w;       w += (size_t)NN * 4 * 2;
    int* bcnt     = (int*)w;          w += (size_t)(NBKT + 4) * 4;
    int* bbase    = (int*)w;          w += (size_t)(NBKT + 4) * 4;
    int* bcur     = (int*)w;          w += (size_t)(NBKT + 4) * 4;
    int* csr      = (int*)w;          w += (size_t)NE * 4;
    __half* sbuf  = (__half*)w;       w += (size_t)NN * 64 * 2;
    float* hbuf   = (float*)w;        w += (size_t)NN * 64 * 4;
    int2* bedges  = (int2*)w;         w += (size_t)NE * 8;

    zero_small_kernel<<<1, 256, 0, stream>>>(bcnt, NBKT);
    bhist_kernel<<<512, 256, 0, stream>>>(dst, bcnt, NE);
    bscan_kernel<<<1, 256, 0, stream>>>(bcnt, bbase, bcur);
    bscatter_kernel<<<512, 256, 0, stream>>>(src, dst, bcur, bedges, NE);
    bfill_kernel<<<NBKT, 256, 0, stream>>>(bedges, bbase, start, ccnt4, dinv, csr);

    const int GB = (NN + 127) / 128;
    const int PB = 1024;  // persistent agg grid: 4 blocks/CU, all co-resident

    gemm_kernel<64><<<GB, 128, 0, stream>>>(x, W1, dinv, sbuf, NN);
    agg64_kernel<true><<<PB, 256, 0, stream>>>(sbuf, csr, start, ccnt4, dinv, b1, hbuf);
    gemm_kernel<64><<<GB, 128, 0, stream>>>(hbuf, W2, dinv, sbuf, NN);
    agg64_kernel<true><<<PB, 256, 0, stream>>>(sbuf, csr, start, ccnt4, dinv, b2, hbuf);
    gemm_kernel<64><<<GB, 128, 0, stream>>>(hbuf, W3, dinv, sbuf, NN);
    agg64_kernel<true><<<PB, 256, 0, stream>>>(sbuf, csr, start, ccnt4, dinv, b3, hbuf);
    gemm_kernel<16><<<GB, 128, 0, stream>>>(hbuf, W4, dinv, sbuf, NN);
    agg16_kernel<<<PB, 256, 0, stream>>>(sbuf, csr, start, ccnt4, dinv, b4, (float*)d_out);
}

// Round 6
// 464.237 us; speedup vs baseline: 2.5864x; 2.5864x over previous
//
#include <hip/hip_runtime.h>
#include <hip/hip_fp16.h>

#define NN 100000
#define NE 1600000
#define BK 512          // nodes per bucket (CSR build)
#define BKSH 9          // log2(BK)
#define NBKT 196        // ceil(NN/BK)

// native clang vector types for nontemporal builtins (HIP float4/uint4 are
// classes -> rejected by __builtin_nontemporal_*)
typedef float  nfloat4 __attribute__((ext_vector_type(4)));
typedef unsigned int nuint4 __attribute__((ext_vector_type(4)));

// ---------------- Bucketed CSR build ----------------

__global__ __launch_bounds__(256) void zero_small_kernel(int* __restrict__ p, int n) {
    int i = threadIdx.x + blockIdx.x * 256;
    if (i < n) p[i] = 0;
}

// per-wave sub-histograms to cut LDS atomic conflicts
__global__ __launch_bounds__(256) void bhist_kernel(const int* __restrict__ dst,
                                                    int* __restrict__ bcnt, int e) {
    __shared__ int h[4 * NBKT];
    int tid = threadIdx.x;
    int wv = tid >> 6;
    for (int i = tid; i < 4 * NBKT; i += 256) h[i] = 0;
    __syncthreads();
    for (int i = blockIdx.x * 256 + tid; i < e; i += gridDim.x * 256)
        atomicAdd(&h[wv * NBKT + (__builtin_nontemporal_load(&dst[i]) >> BKSH)], 1);
    __syncthreads();
    for (int i = tid; i < NBKT; i += 256) {
        int s = h[i] + h[NBKT + i] + h[2 * NBKT + i] + h[3 * NBKT + i];
        if (s) atomicAdd(&bcnt[i], s);
    }
}

__global__ __launch_bounds__(256) void bscan_kernel(const int* __restrict__ bcnt,
                                                    int* __restrict__ bbase,
                                                    int* __restrict__ bcur) {
    __shared__ int sc[256];
    int tid = threadIdx.x;
    int v = (tid < NBKT) ? bcnt[tid] : 0;
    sc[tid] = v;
    __syncthreads();
    for (int off = 1; off < 256; off <<= 1) {
        int t2 = (tid >= off) ? sc[tid - off] : 0;
        __syncthreads();
        sc[tid] += t2;
        __syncthreads();
    }
    if (tid < NBKT) {
        int ex = sc[tid] - v;
        bbase[tid] = ex;
        bcur[tid] = ex;
    }
    if (tid == 255) bbase[NBKT] = sc[255];
}

// Counting-sort edges into dst-bucket order. Tile = 2048 edges, LDS reorder.
__global__ __launch_bounds__(256) void bscatter_kernel(const int* __restrict__ src,
                                                       const int* __restrict__ dst,
                                                       int* __restrict__ bcur,
                                                       int2* __restrict__ bedges, int e) {
    __shared__ int h[256];
    __shared__ int sc[256];
    __shared__ int gb[NBKT];
    __shared__ int2 stage[2048];
    int tid = threadIdx.x;
    for (int tile = blockIdx.x * 2048; tile < e; tile += gridDim.x * 2048) {
        int cnt_tile = min(2048, e - tile);
        h[tid] = 0;
        __syncthreads();
        int2 pr[8]; int rk[8]; int bk[8];
#pragma unroll
        for (int j = 0; j < 8; j++) {
            int li = tid + j * 256;
            if (li < cnt_tile) {
                pr[j].x = src[tile + li];
                pr[j].y = dst[tile + li];
                bk[j] = pr[j].y >> BKSH;
                rk[j] = atomicAdd(&h[bk[j]], 1);
            } else bk[j] = -1;
        }
        __syncthreads();
        int v = h[tid];
        sc[tid] = v;
        __syncthreads();
        for (int off = 1; off < 256; off <<= 1) {
            int t2 = (tid >= off) ? sc[tid - off] : 0;
            __syncthreads();
            sc[tid] += t2;
            __syncthreads();
        }
        int excl = sc[tid] - v;
        if (tid < NBKT && v > 0) gb[tid] = atomicAdd(&bcur[tid], v);
        __syncthreads();
        sc[tid] = excl;
        __syncthreads();
#pragma unroll
        for (int j = 0; j < 8; j++)
            if (bk[j] >= 0) stage[sc[bk[j]] + rk[j]] = pr[j];
        __syncthreads();
#pragma unroll
        for (int j = 0; j < 8; j++) {
            int li = tid + j * 256;
            if (li < cnt_tile) {
                int2 p2 = stage[li];
                int b = p2.y >> BKSH;
                bedges[gb[b] + (li - sc[b])] = p2;
            }
        }
        __syncthreads();
    }
}

// One block per bucket: LDS degree hist + scan + cursor placement.
__global__ __launch_bounds__(256) void bfill_kernel(const int2* __restrict__ bedges,
                                                    const int* __restrict__ bbase,
                                                    int* __restrict__ start,
                                                    int* __restrict__ cnt,
                                                    float* __restrict__ dinv,
                                                    int* __restrict__ csr) {
    __shared__ int lcnt[BK];
    __shared__ int lsum[256];
    __shared__ int lstart[BK];
    __shared__ int lcur[BK];
    int q = blockIdx.x, tid = threadIdx.x;
    int ebase = bbase[q], ec = bbase[q + 1] - ebase;
    int nbase = q * BK;
    lcnt[tid] = 0; lcnt[tid + 256] = 0;
    __syncthreads();
    for (int i = tid; i < ec; i += 256)
        atomicAdd(&lcnt[bedges[ebase + i].y - nbase], 1);
    __syncthreads();
    int a = lcnt[2 * tid], b = lcnt[2 * tid + 1];
    int s = a + b;
    lsum[tid] = s;
    __syncthreads();
    for (int off = 1; off < 256; off <<= 1) {
        int t2 = (tid >= off) ? lsum[tid - off] : 0;
        __syncthreads();
        lsum[tid] += t2;
        __syncthreads();
    }
    int ex = lsum[tid] - s;
    lstart[2 * tid] = ex;       lstart[2 * tid + 1] = ex + a;
    lcur[2 * tid] = ex;         lcur[2 * tid + 1] = ex + a;
    __syncthreads();
    for (int l = tid; l < BK; l += 256) {
        int v = nbase + l;
        if (v < NN) {
            start[v] = ebase + lstart[l];
            cnt[v]   = lcnt[l];
            dinv[v]  = rsqrtf((float)lcnt[l] + 1.0f);
        }
    }
    for (int i = tid; i < ec; i += 256) {
        int2 p2 = bedges[ebase + i];
        int r = atomicAdd(&lcur[p2.y - nbase], 1);
        csr[ebase + r] = p2.x;
    }
}

// ---------------- GEMM: s = half( dinv .* (x @ W) ) ----------------
// HALF_IN: input feature matrix stored fp16 (hidden layers); else fp32.
template <int DOUT, bool HALF_IN>
__global__ __launch_bounds__(128) void gemm_kernel(const void* __restrict__ xin,
                                                   const float* __restrict__ W,
                                                   const float* __restrict__ dinv,
                                                   __half* __restrict__ s, int n) {
    constexpr int G = DOUT / 16;
    constexpr int R = G;
    constexpr int ROWS = 128;
    __shared__ float xs[ROWS][65];
    __shared__ float ws[64][DOUT];
    int tid = threadIdx.x;
    int row0 = blockIdx.x * ROWS;
    for (int i = tid; i < 64 * DOUT; i += 128) ws[i / DOUT][i % DOUT] = W[i];
    for (int i = tid; i < ROWS * 16; i += 128) {
        int r = i >> 4, c = (i & 15) * 4;
        float4 v = make_float4(0.f, 0.f, 0.f, 0.f);
        if (row0 + r < n) {
            if constexpr (HALF_IN) {
                const unsigned int* hp =
                    (const unsigned int*)((const __half*)xin + (size_t)(row0 + r) * 64 + c);
                unsigned int u01 = __builtin_nontemporal_load(&hp[0]);
                unsigned int u23 = __builtin_nontemporal_load(&hp[1]);
                __half2 h01 = *(__half2*)&u01;
                __half2 h23 = *(__half2*)&u23;
                float2 f01 = __half22float2(h01);
                float2 f23 = __half22float2(h23);
                v = make_float4(f01.x, f01.y, f23.x, f23.y);
            } else {
                nfloat4 nv = __builtin_nontemporal_load(
                    (const nfloat4*)((const float*)xin + (size_t)(row0 + r) * 64 + c));
                v = make_float4(nv.x, nv.y, nv.z, nv.w);
            }
        }
        xs[r][c] = v.x; xs[r][c + 1] = v.y; xs[r][c + 2] = v.z; xs[r][c + 3] = v.w;
    }
    __syncthreads();
    int cg = tid % G;
    int rbase = (tid / G) * R;
    float acc[R][16];
#pragma unroll
    for (int i = 0; i < R; i++)
#pragma unroll
        for (int j = 0; j < 16; j++) acc[i][j] = 0.f;
    for (int k = 0; k < 64; k++) {
        float xv[R];
#pragma unroll
        for (int i = 0; i < R; i++) xv[i] = xs[rbase + i][k];
#pragma unroll
        for (int j = 0; j < 4; j++) {
            float4 wv = *(const float4*)&ws[k][cg * 16 + j * 4];
#pragma unroll
            for (int i = 0; i < R; i++) {
                acc[i][j * 4 + 0] += xv[i] * wv.x;
                acc[i][j * 4 + 1] += xv[i] * wv.y;
                acc[i][j * 4 + 2] += xv[i] * wv.z;
                acc[i][j * 4 + 3] += xv[i] * wv.w;
            }
        }
    }
#pragma unroll
    for (int i = 0; i < R; i++) {
        int r = row0 + rbase + i;
        if (r < n) {
            float dv = dinv[r];
            union { ushort u[16]; nuint4 q[2]; } pk;
#pragma unroll
            for (int j = 0; j < 16; j++)
                pk.u[j] = __half_as_ushort(__float2half_rn(acc[i][j] * dv));
            nuint4* sp = (nuint4*)&s[(size_t)r * DOUT + cg * 16];
            __builtin_nontemporal_store(pk.q[0], &sp[0]);
            __builtin_nontemporal_store(pk.q[1], &sp[1]);
        }
    }
}

// ---------------- Aggregate: out[v] = act(dinv[v]*(s[v] + sum s[u]) + b) ----------------
// R3 structure: one node per D lanes, huge grid, 8-deep independent gather window.
// csr loads + out stores nontemporal so they don't evict gather-hot s lines in L2.
template <int D, bool RELU, bool HALF_OUT>
__global__ __launch_bounds__(256) void agg_kernel(const __half* __restrict__ s,
                                                  const int* __restrict__ csr,
                                                  const int* __restrict__ start,
                                                  const int* __restrict__ cnt,
                                                  const float* __restrict__ dinv,
                                                  const float* __restrict__ bias,
                                                  void* __restrict__ out, int n) {
    constexpr int NPW = 64 / D;
    int tid = threadIdx.x;
    int lane = tid & 63;
    int wave = tid >> 6;
    int col = lane % D;
    int grp = lane / D;
    int node = (blockIdx.x * (256 / 64) + wave) * NPW + grp;
    if (node >= n) return;
    int st = start[node];
    int cn = cnt[node];
    if constexpr (D == 64) {   // node is wave-uniform -> scalarize headers
        st = __builtin_amdgcn_readfirstlane(st);
        cn = __builtin_amdgcn_readfirstlane(cn);
    }
    float acc = __half2float(s[(size_t)node * D + col]);  // self loop
    int e = 0;
    for (; e + 7 < cn; e += 8) {
        int u[8]; float a[8];
#pragma unroll
        for (int j = 0; j < 8; j++) u[j] = __builtin_nontemporal_load(&csr[st + e + j]);
#pragma unroll
        for (int j = 0; j < 8; j++) a[j] = __half2float(s[(size_t)u[j] * D + col]);
        acc += ((a[0] + a[1]) + (a[2] + a[3])) + ((a[4] + a[5]) + (a[6] + a[7]));
    }
    for (; e + 3 < cn; e += 4) {
        int u0 = __builtin_nontemporal_load(&csr[st + e + 0]);
        int u1 = __builtin_nontemporal_load(&csr[st + e + 1]);
        int u2 = __builtin_nontemporal_load(&csr[st + e + 2]);
        int u3 = __builtin_nontemporal_load(&csr[st + e + 3]);
        float a0 = __half2float(s[(size_t)u0 * D + col]);
        float a1 = __half2float(s[(size_t)u1 * D + col]);
        float a2 = __half2float(s[(size_t)u2 * D + col]);
        float a3 = __half2float(s[(size_t)u3 * D + col]);
        acc += (a0 + a1) + (a2 + a3);
    }
    for (; e < cn; e++) {
        int u = __builtin_nontemporal_load(&csr[st + e]);
        acc += __half2float(s[(size_t)u * D + col]);
    }
    float o = dinv[node] * acc + bias[col];
    if (RELU) o = fmaxf(o, 0.f);
    if constexpr (HALF_OUT) {
        ushort h = __half_as_ushort(__float2half_rn(o));
        __builtin_nontemporal_store(h, (ushort*)out + (size_t)node * D + col);
    } else {
        __builtin_nontemporal_store(o, (float*)out + (size_t)node * D + col);
    }
}

// ---------------- launch ----------------

extern "C" void kernel_launch(void* const* d_in, const int* in_sizes, int n_in,
                              void* d_out, int out_size, void* d_ws, size_t ws_size,
                              hipStream_t stream) {
    const float* x  = (const float*)d_in[0];
    const int* ei   = (const int*)d_in[1];
    const float* W1 = (const float*)d_in[2];
    const float* b1 = (const float*)d_in[3];
    const float* W2 = (const float*)d_in[4];
    const float* b2 = (const float*)d_in[5];
    const float* W3 = (const float*)d_in[6];
    const float* b3 = (const float*)d_in[7];
    const float* W4 = (const float*)d_in[8];
    const float* b4 = (const float*)d_in[9];
    const int* src = ei;
    const int* dst = ei + NE;

    char* w = (char*)d_ws;
    float* dinv  = (float*)w;         w += (size_t)NN * 4;
    int* cnt     = (int*)w;           w += (size_t)NN * 4;
    int* start   = (int*)w;           w += (size_t)NN * 4;
    int* bcnt    = (int*)w;           w += (size_t)(NBKT + 4) * 4;
    int* bbase   = (int*)w;           w += (size_t)(NBKT + 4) * 4;
    int* bcur    = (int*)w;           w += (size_t)(NBKT + 4) * 4;
    int* csr     = (int*)w;           w += (size_t)NE * 4;
    __half* sbuf = (__half*)w;        w += (size_t)NN * 64 * 2;
    __half* hbuf = (__half*)w;        w += (size_t)NN * 64 * 2;
    int2* bedges = (int2*)w;          w += (size_t)NE * 8;

    zero_small_kernel<<<1, 256, 0, stream>>>(bcnt, NBKT);
    bhist_kernel<<<512, 256, 0, stream>>>(dst, bcnt, NE);
    bscan_kernel<<<1, 256, 0, stream>>>(bcnt, bbase, bcur);
    bscatter_kernel<<<512, 256, 0, stream>>>(src, dst, bcur, bedges, NE);
    bfill_kernel<<<NBKT, 256, 0, stream>>>(bedges, bbase, start, cnt, dinv, csr);

    const int GB = (NN + 127) / 128;
    const int AB64 = (NN + 3) / 4;
    const int AB16 = (NN + 15) / 16;

    gemm_kernel<64, false><<<GB, 128, 0, stream>>>(x, W1, dinv, sbuf, NN);
    agg_kernel<64, true, true><<<AB64, 256, 0, stream>>>(sbuf, csr, start, cnt, dinv, b1, hbuf, NN);
    gemm_kernel<64, true><<<GB, 128, 0, stream>>>(hbuf, W2, dinv, sbuf, NN);
    agg_kernel<64, true, true><<<AB64, 256, 0, stream>>>(sbuf, csr, start, cnt, dinv, b2, hbuf, NN);
    gemm_kernel<64, true><<<GB, 128, 0, stream>>>(hbuf, W3, dinv, sbuf, NN);
    agg_kernel<64, true, true><<<AB64, 256, 0, stream>>>(sbuf, csr, start, cnt, dinv, b3, hbuf, NN);
    gemm_kernel<16, true><<<GB, 128, 0, stream>>>(hbuf, W4, dinv, sbuf, NN);
    agg_kernel<16, false, false><<<AB16, 256, 0, stream>>>(sbuf, csr, start, cnt, dinv, b4, d_out, NN);
}

// Round 7
// 409.365 us; speedup vs baseline: 2.9330x; 1.1340x over previous
//
#include <hip/hip_runtime.h>
#include <hip/hip_fp16.h>

#define NN 100000
#define NE 1600000
#define BK 512          // nodes per bucket (CSR build)
#define BKSH 9          // log2(BK)
#define NBKT 196        // ceil(NN/BK)

// ---------------- Bucketed CSR build (unchanged from R6) ----------------

__global__ __launch_bounds__(256) void zero_small_kernel(int* __restrict__ p, int n) {
    int i = threadIdx.x + blockIdx.x * 256;
    if (i < n) p[i] = 0;
}

__global__ __launch_bounds__(256) void bhist_kernel(const int* __restrict__ dst,
                                                    int* __restrict__ bcnt, int e) {
    __shared__ int h[4 * NBKT];
    int tid = threadIdx.x;
    int wv = tid >> 6;
    for (int i = tid; i < 4 * NBKT; i += 256) h[i] = 0;
    __syncthreads();
    for (int i = blockIdx.x * 256 + tid; i < e; i += gridDim.x * 256)
        atomicAdd(&h[wv * NBKT + (__builtin_nontemporal_load(&dst[i]) >> BKSH)], 1);
    __syncthreads();
    for (int i = tid; i < NBKT; i += 256) {
        int s = h[i] + h[NBKT + i] + h[2 * NBKT + i] + h[3 * NBKT + i];
        if (s) atomicAdd(&bcnt[i], s);
    }
}

__global__ __launch_bounds__(256) void bscan_kernel(const int* __restrict__ bcnt,
                                                    int* __restrict__ bbase,
                                                    int* __restrict__ bcur) {
    __shared__ int sc[256];
    int tid = threadIdx.x;
    int v = (tid < NBKT) ? bcnt[tid] : 0;
    sc[tid] = v;
    __syncthreads();
    for (int off = 1; off < 256; off <<= 1) {
        int t2 = (tid >= off) ? sc[tid - off] : 0;
        __syncthreads();
        sc[tid] += t2;
        __syncthreads();
    }
    if (tid < NBKT) {
        int ex = sc[tid] - v;
        bbase[tid] = ex;
        bcur[tid] = ex;
    }
    if (tid == 255) bbase[NBKT] = sc[255];
}

__global__ __launch_bounds__(256) void bscatter_kernel(const int* __restrict__ src,
                                                       const int* __restrict__ dst,
                                                       int* __restrict__ bcur,
                                                       int2* __restrict__ bedges, int e) {
    __shared__ int h[256];
    __shared__ int sc[256];
    __shared__ int gb[NBKT];
    __shared__ int2 stage[2048];
    int tid = threadIdx.x;
    for (int tile = blockIdx.x * 2048; tile < e; tile += gridDim.x * 2048) {
        int cnt_tile = min(2048, e - tile);
        h[tid] = 0;
        __syncthreads();
        int2 pr[8]; int rk[8]; int bk[8];
#pragma unroll
        for (int j = 0; j < 8; j++) {
            int li = tid + j * 256;
            if (li < cnt_tile) {
                pr[j].x = src[tile + li];
                pr[j].y = dst[tile + li];
                bk[j] = pr[j].y >> BKSH;
                rk[j] = atomicAdd(&h[bk[j]], 1);
            } else bk[j] = -1;
        }
        __syncthreads();
        int v = h[tid];
        sc[tid] = v;
        __syncthreads();
        for (int off = 1; off < 256; off <<= 1) {
            int t2 = (tid >= off) ? sc[tid - off] : 0;
            __syncthreads();
            sc[tid] += t2;
            __syncthreads();
        }
        int excl = sc[tid] - v;
        if (tid < NBKT && v > 0) gb[tid] = atomicAdd(&bcur[tid], v);
        __syncthreads();
        sc[tid] = excl;
        __syncthreads();
#pragma unroll
        for (int j = 0; j < 8; j++)
            if (bk[j] >= 0) stage[sc[bk[j]] + rk[j]] = pr[j];
        __syncthreads();
#pragma unroll
        for (int j = 0; j < 8; j++) {
            int li = tid + j * 256;
            if (li < cnt_tile) {
                int2 p2 = stage[li];
                int b = p2.y >> BKSH;
                bedges[gb[b] + (li - sc[b])] = p2;
            }
        }
        __syncthreads();
    }
}

__global__ __launch_bounds__(256) void bfill_kernel(const int2* __restrict__ bedges,
                                                    const int* __restrict__ bbase,
                                                    int* __restrict__ start,
                                                    int* __restrict__ cnt,
                                                    float* __restrict__ dinv,
                                                    int* __restrict__ csr) {
    __shared__ int lcnt[BK];
    __shared__ int lsum[256];
    __shared__ int lstart[BK];
    __shared__ int lcur[BK];
    int q = blockIdx.x, tid = threadIdx.x;
    int ebase = bbase[q], ec = bbase[q + 1] - ebase;
    int nbase = q * BK;
    lcnt[tid] = 0; lcnt[tid + 256] = 0;
    __syncthreads();
    for (int i = tid; i < ec; i += 256)
        atomicAdd(&lcnt[bedges[ebase + i].y - nbase], 1);
    __syncthreads();
    int a = lcnt[2 * tid], b = lcnt[2 * tid + 1];
    int s = a + b;
    lsum[tid] = s;
    __syncthreads();
    for (int off = 1; off < 256; off <<= 1) {
        int t2 = (tid >= off) ? lsum[tid - off] : 0;
        __syncthreads();
        lsum[tid] += t2;
        __syncthreads();
    }
    int ex = lsum[tid] - s;
    lstart[2 * tid] = ex;       lstart[2 * tid + 1] = ex + a;
    lcur[2 * tid] = ex;         lcur[2 * tid + 1] = ex + a;
    __syncthreads();
    for (int l = tid; l < BK; l += 256) {
        int v = nbase + l;
        if (v < NN) {
            start[v] = ebase + lstart[l];
            cnt[v]   = lcnt[l];
            dinv[v]  = rsqrtf((float)lcnt[l] + 1.0f);
        }
    }
    for (int i = tid; i < ec; i += 256) {
        int2 p2 = bedges[ebase + i];
        int r = atomicAdd(&lcur[p2.y - nbase], 1);
        csr[ebase + r] = p2.x;
    }
}

// ---------------- prep: g0 = fp16(dinv .* x) ----------------
__global__ __launch_bounds__(256) void prep_kernel(const float* __restrict__ x,
                                                   const float* __restrict__ dinv,
                                                   __half* __restrict__ g) {
    size_t i4 = (size_t)blockIdx.x * 256 + threadIdx.x;   // float4 index
    if (i4 >= (size_t)NN * 16) return;
    int row = (int)(i4 >> 4);
    float dv = dinv[row];
    float4 v = *(const float4*)&x[i4 * 4];
    __half2 h01 = __floats2half2_rn(v.x * dv, v.y * dv);
    __half2 h23 = __floats2half2_rn(v.z * dv, v.w * dv);
    __half2* gp = (__half2*)&g[i4 * 4];
    gp[0] = h01;
    gp[1] = h23;
}

// ---------------- Fused layer (1-3): gather + 64x64 transform ----------------
// g = dinv.*h stored fp16. Per node v:
//   z = sum_{u in N(v) u {v}} g[u]            (the R6 agg64 gather, fp32 acc)
//   t = dinv[v] * (z @ W) + b ; h' = relu(t) ; g' = dinv[v] * h'
// 512 threads = 8 waves = 8 nodes/block; W (16KB) + bias in LDS.
__global__ __launch_bounds__(512) void fused_layer_kernel(const __half* __restrict__ g,
                                                          const int* __restrict__ csr,
                                                          const int* __restrict__ start,
                                                          const int* __restrict__ cnt,
                                                          const float* __restrict__ dinv,
                                                          const float* __restrict__ Wg,
                                                          const float* __restrict__ bias,
                                                          __half* __restrict__ gout, int n) {
    __shared__ float wsm[64][64];   // W[l][c]; lane=c reads bank c%32 -> 2-way (free)
    __shared__ float zs[8][64];
    __shared__ float bs[64];
    int tid = threadIdx.x;
    {   // stage W: 1024 float4, 512 threads x 2
        const float4* Wv = (const float4*)Wg;
        float4* wv4 = (float4*)&wsm[0][0];
        wv4[tid] = Wv[tid];
        wv4[tid + 512] = Wv[tid + 512];
    }
    if (tid < 64) bs[tid] = bias[tid];
    __syncthreads();

    int wv = tid >> 6, lane = tid & 63;
    int node = blockIdx.x * 8 + wv;
    float acc = 0.f;
    float dv = 0.f;
    if (node < n) {
        int st = __builtin_amdgcn_readfirstlane(start[node]);
        int cn = __builtin_amdgcn_readfirstlane(cnt[node]);
        dv = dinv[node];
        acc = __half2float(g[(size_t)node * 64 + lane]);  // self loop
        int e = 0;
        for (; e + 7 < cn; e += 8) {
            int u[8]; float a[8];
#pragma unroll
            for (int j = 0; j < 8; j++) u[j] = __builtin_nontemporal_load(&csr[st + e + j]);
#pragma unroll
            for (int j = 0; j < 8; j++) a[j] = __half2float(g[(size_t)u[j] * 64 + lane]);
            acc += ((a[0] + a[1]) + (a[2] + a[3])) + ((a[4] + a[5]) + (a[6] + a[7]));
        }
        for (; e + 3 < cn; e += 4) {
            int u0 = __builtin_nontemporal_load(&csr[st + e + 0]);
            int u1 = __builtin_nontemporal_load(&csr[st + e + 1]);
            int u2 = __builtin_nontemporal_load(&csr[st + e + 2]);
            int u3 = __builtin_nontemporal_load(&csr[st + e + 3]);
            float a0 = __half2float(g[(size_t)u0 * 64 + lane]);
            float a1 = __half2float(g[(size_t)u1 * 64 + lane]);
            float a2 = __half2float(g[(size_t)u2 * 64 + lane]);
            float a3 = __half2float(g[(size_t)u3 * 64 + lane]);
            acc += (a0 + a1) + (a2 + a3);
        }
        for (; e < cn; e++) {
            int u = __builtin_nontemporal_load(&csr[st + e]);
            acc += __half2float(g[(size_t)u * 64 + lane]);
        }
    }
    zs[wv][lane] = acc;
    __syncthreads();
    if (node < n) {
        float t = 0.f;
#pragma unroll
        for (int l = 0; l < 64; l += 4) {
            float4 zq = *(const float4*)&zs[wv][l];   // wave-uniform addr: broadcast
            t += zq.x * wsm[l][lane];
            t += zq.y * wsm[l + 1][lane];
            t += zq.z * wsm[l + 2][lane];
            t += zq.w * wsm[l + 3][lane];
        }
        t = dv * t + bs[lane];
        t = fmaxf(t, 0.f);
        gout[(size_t)node * 64 + lane] = __float2half_rn(dv * t);
    }
}

// ---------------- Layer-4 transform: s4 = g3 @ W4  (dinv cancels exactly) ----------------
__global__ __launch_bounds__(128) void gemm16_kernel(const __half* __restrict__ xin,
                                                     const float* __restrict__ W,
                                                     __half* __restrict__ s, int n) {
    constexpr int DOUT = 16;
    constexpr int ROWS = 128;
    __shared__ float xs[ROWS][65];
    __shared__ float ws[64][DOUT];
    int tid = threadIdx.x;
    int row0 = blockIdx.x * ROWS;
    for (int i = tid; i < 64 * DOUT; i += 128) ws[i / DOUT][i % DOUT] = W[i];
    for (int i = tid; i < ROWS * 16; i += 128) {
        int r = i >> 4, c = (i & 15) * 4;
        float4 v = make_float4(0.f, 0.f, 0.f, 0.f);
        if (row0 + r < n) {
            const __half* hp = xin + (size_t)(row0 + r) * 64 + c;
            float2 f01 = __half22float2(*(const __half2*)hp);
            float2 f23 = __half22float2(*(const __half2*)(hp + 2));
            v = make_float4(f01.x, f01.y, f23.x, f23.y);
        }
        xs[r][c] = v.x; xs[r][c + 1] = v.y; xs[r][c + 2] = v.z; xs[r][c + 3] = v.w;
    }
    __syncthreads();
    int rbase = tid;           // 1 row per thread
    float acc[16];
#pragma unroll
    for (int j = 0; j < 16; j++) acc[j] = 0.f;
    for (int k = 0; k < 64; k++) {
        float xv = xs[rbase][k];
#pragma unroll
        for (int j = 0; j < 4; j++) {
            float4 wv = *(const float4*)&ws[k][j * 4];
            acc[j * 4 + 0] += xv * wv.x;
            acc[j * 4 + 1] += xv * wv.y;
            acc[j * 4 + 2] += xv * wv.z;
            acc[j * 4 + 3] += xv * wv.w;
        }
    }
    int r = row0 + rbase;
    if (r < n) {
        union { ushort u[16]; uint4 q[2]; } pk;
#pragma unroll
        for (int j = 0; j < 16; j++)
            pk.u[j] = __half_as_ushort(__float2half_rn(acc[j]));
        uint4* sp = (uint4*)&s[(size_t)r * DOUT];
        sp[0] = pk.q[0];
        sp[1] = pk.q[1];
    }
}

// ---------------- Layer-4 aggregate: out = dinv*(sum s4) + b4, fp32 ----------------
__global__ __launch_bounds__(256) void agg16_kernel(const __half* __restrict__ s,
                                                    const int* __restrict__ csr,
                                                    const int* __restrict__ start,
                                                    const int* __restrict__ cnt,
                                                    const float* __restrict__ dinv,
                                                    const float* __restrict__ bias,
                                                    float* __restrict__ out, int n) {
    constexpr int D = 16;
    int tid = threadIdx.x;
    int lane = tid & 63;
    int wave = tid >> 6;
    int col = lane % D;
    int grp = lane / D;
    int node = (blockIdx.x * 4 + wave) * 4 + grp;
    if (node >= n) return;
    int st = start[node];
    int cn = cnt[node];
    float acc = __half2float(s[(size_t)node * D + col]);  // self loop
    int e = 0;
    for (; e + 7 < cn; e += 8) {
        int u[8]; float a[8];
#pragma unroll
        for (int j = 0; j < 8; j++) u[j] = __builtin_nontemporal_load(&csr[st + e + j]);
#pragma unroll
        for (int j = 0; j < 8; j++) a[j] = __half2float(s[(size_t)u[j] * D + col]);
        acc += ((a[0] + a[1]) + (a[2] + a[3])) + ((a[4] + a[5]) + (a[6] + a[7]));
    }
    for (; e + 3 < cn; e += 4) {
        int u0 = __builtin_nontemporal_load(&csr[st + e + 0]);
        int u1 = __builtin_nontemporal_load(&csr[st + e + 1]);
        int u2 = __builtin_nontemporal_load(&csr[st + e + 2]);
        int u3 = __builtin_nontemporal_load(&csr[st + e + 3]);
        float a0 = __half2float(s[(size_t)u0 * D + col]);
        float a1 = __half2float(s[(size_t)u1 * D + col]);
        float a2 = __half2float(s[(size_t)u2 * D + col]);
        float a3 = __half2float(s[(size_t)u3 * D + col]);
        acc += (a0 + a1) + (a2 + a3);
    }
    for (; e < cn; e++) {
        int u = __builtin_nontemporal_load(&csr[st + e]);
        acc += __half2float(s[(size_t)u * D + col]);
    }
    float o = dinv[node] * acc + bias[col];
    __builtin_nontemporal_store(o, out + (size_t)node * D + col);
}

// ---------------- launch ----------------

extern "C" void kernel_launch(void* const* d_in, const int* in_sizes, int n_in,
                              void* d_out, int out_size, void* d_ws, size_t ws_size,
                              hipStream_t stream) {
    const float* x  = (const float*)d_in[0];
    const int* ei   = (const int*)d_in[1];
    const float* W1 = (const float*)d_in[2];
    const float* b1 = (const float*)d_in[3];
    const float* W2 = (const float*)d_in[4];
    const float* b2 = (const float*)d_in[5];
    const float* W3 = (const float*)d_in[6];
    const float* b3 = (const float*)d_in[7];
    const float* W4 = (const float*)d_in[8];
    const float* b4 = (const float*)d_in[9];
    const int* src = ei;
    const int* dst = ei + NE;

    char* w = (char*)d_ws;
    float* dinv  = (float*)w;         w += (size_t)NN * 4;
    int* cnt     = (int*)w;           w += (size_t)NN * 4;
    int* start   = (int*)w;           w += (size_t)NN * 4;
    int* bcnt    = (int*)w;           w += (size_t)(NBKT + 4) * 4;
    int* bbase   = (int*)w;           w += (size_t)(NBKT + 4) * 4;
    int* bcur    = (int*)w;           w += (size_t)(NBKT + 4) * 4;
    int* csr     = (int*)w;           w += (size_t)NE * 4;
    __half* gA   = (__half*)w;        w += (size_t)NN * 64 * 2;
    __half* gB   = (__half*)w;        w += (size_t)NN * 64 * 2;
    __half* s4   = (__half*)w;        w += (size_t)NN * 16 * 2;
    int2* bedges = (int2*)w;          w += (size_t)NE * 8;

    zero_small_kernel<<<1, 256, 0, stream>>>(bcnt, NBKT);
    bhist_kernel<<<512, 256, 0, stream>>>(dst, bcnt, NE);
    bscan_kernel<<<1, 256, 0, stream>>>(bcnt, bbase, bcur);
    bscatter_kernel<<<512, 256, 0, stream>>>(src, dst, bcur, bedges, NE);
    bfill_kernel<<<NBKT, 256, 0, stream>>>(bedges, bbase, start, cnt, dinv, csr);

    prep_kernel<<<(NN * 16 + 255) / 256, 256, 0, stream>>>(x, dinv, gA);

    const int FB = (NN + 7) / 8;      // 12500 blocks, 8 nodes each
    fused_layer_kernel<<<FB, 512, 0, stream>>>(gA, csr, start, cnt, dinv, W1, b1, gB, NN);
    fused_layer_kernel<<<FB, 512, 0, stream>>>(gB, csr, start, cnt, dinv, W2, b2, gA, NN);
    fused_layer_kernel<<<FB, 512, 0, stream>>>(gA, csr, start, cnt, dinv, W3, b3, gB, NN);

    const int GB = (NN + 127) / 128;
    const int AB16 = (NN + 15) / 16;
    gemm16_kernel<<<GB, 128, 0, stream>>>(gB, W4, s4, NN);
    agg16_kernel<<<AB16, 256, 0, stream>>>(s4, csr, start, cnt, dinv, b4, (float*)d_out, NN);
}